// Round 6
// baseline (945.952 us; speedup 1.0000x reference)
//
#include <hip/hip_runtime.h>
#include <math.h>

#define T_LEN 3000
#define HID 64

typedef _Float16 f16;
typedef f16 f16x8 __attribute__((ext_vector_type(8)));
typedef float f32x4 __attribute__((ext_vector_type(4)));

__device__ __forceinline__ float sigmoid_f(float v) {
    return __builtin_amdgcn_rcpf(1.0f + __expf(-v));
}
__device__ __forceinline__ float tanh_f(float v) {
    return fmaf(2.0f, __builtin_amdgcn_rcpf(1.0f + __expf(-2.0f * v)), -1.0f);
}
__device__ __forceinline__ float bcast_lane(float v, int j) {
    return __builtin_bit_cast(float,
        __builtin_amdgcn_readlane(__builtin_bit_cast(int, v), j));
}

// R12: two independent batch elements per block.
// R11 budget (497cy/step): 96cy MFMA wave-block + ~178cy VALU + ~220cy STALL
// (ds_read h latency ~120cy un-hideable after the barrier, trans chains,
// barrier drain). The stall is dead time on a serial chain -> fill it with a
// SECOND independent recurrence: element 1's MFMAs/gates issue while element
// 0 stalls. Weights shared (same Bf, same per-unit scalars). 12 MFMA/wave,
// 4 pipelined ds_reads, interleaved gate chains, ONE barrier per step.
// Barrier: raw s_waitcnt lgkmcnt(0)+s_barrier (asm, memory clobber) instead
// of __syncthreads -> no vmcnt(0) drain, so the 64-step x-prefetch slack
// survives (syncthreads was eating a full HBM latency every 64th step).
// Fragment math identical to R11 (harness-verified, absmax 4.9e-4).
__global__ __launch_bounds__(256, 1)
void gru_2batch(
    const float* __restrict__ x,     // (B, T, 1)
    const float* __restrict__ W_ih,  // (192, 1)
    const float* __restrict__ W_hh,  // (192, 64)
    const float* __restrict__ b_ih,  // (192,)
    const float* __restrict__ b_hh,  // (192,)
    const float* __restrict__ W_fc,  // (1, 64)
    const float* __restrict__ b_fc,  // (1,)
    float* __restrict__ out)         // (B,)
{
    const int tid = threadIdx.x;
    const int w   = tid >> 6;      // wave 0..3 -> owns units 16w..16w+15
    const int l   = tid & 63;
    const int col = l & 15;
    const int grp = l >> 4;        // k-group (redundant dim for gate math)
    const int u   = 16 * w + col;  // this lane's hidden unit
    const int b0  = 2 * blockIdx.x;
    const long xb0 = (long)b0 * T_LEN;
    const long xb1 = xb0 + T_LEN;

    __shared__ __align__(16) f16 hbuf[2][2][HID];  // [pingpong][elem][unit]
    __shared__ float hf32[2][HID];

    // ---- one-time: this wave's W_hh tiles -> B fragments (f16) ----
    // B slot (lane, elem j) = W_hh[64*g + 16*w + col][8*grp + 32*hf + j]
    f16x8 Bf[3][2];
#pragma unroll
    for (int g = 0; g < 3; ++g) {
#pragma unroll
        for (int hf = 0; hf < 2; ++hf) {
            const float* p = W_hh + (size_t)(64 * g + 16 * w + col) * HID
                           + 8 * grp + 32 * hf;
            const float4 a = *reinterpret_cast<const float4*>(p);
            const float4 c = *reinterpret_cast<const float4*>(p + 4);
            f16x8 v;
            v[0] = (f16)a.x; v[1] = (f16)a.y; v[2] = (f16)a.z; v[3] = (f16)a.w;
            v[4] = (f16)c.x; v[5] = (f16)c.y; v[6] = (f16)c.z; v[7] = (f16)c.w;
            Bf[g][hf] = v;
        }
    }

    // per-unit scalars (shared by both elements)
    const float wihr = W_ih[u],        wihz = W_ih[64 + u],   wihn = W_ih[128 + u];
    const float br   = b_ih[u]        + b_hh[u];
    const float bz   = b_ih[64 + u]   + b_hh[64 + u];
    const float bin  = b_ih[128 + u];
    const float bhn  = b_hh[128 + u];

    // x windows in registers (lane j holds x[t0+j]); readlane broadcast
    float xw0 = x[xb0 + l];
    float xw1 = x[xb1 + l];
    float xn0 = (64 + l < T_LEN) ? x[xb0 + 64 + l] : 0.0f;
    float xn1 = (64 + l < T_LEN) ? x[xb1 + 64 + l] : 0.0f;

    if (tid < 2 * HID) reinterpret_cast<f16*>(hbuf[0])[tid] = (f16)0.0f;
    __syncthreads();

    float h0 = 0.0f, h1 = 0.0f;   // this lane's unit value for each element
    const f32x4 zf = {0.f, 0.f, 0.f, 0.f};

    auto step = [&](const f16(*src)[HID], f16(*dst)[HID], int t) {
        const int j = t & 63;
        const float xt0 = bcast_lane(xw0, j);
        const float xt1 = bcast_lane(xw1, j);
        const float gxr0 = fmaf(xt0, wihr, br);
        const float gxz0 = fmaf(xt0, wihz, bz);
        const float gxn0 = fmaf(xt0, wihn, bin);
        const float gxr1 = fmaf(xt1, wihr, br);
        const float gxz1 = fmaf(xt1, wihz, bz);
        const float gxn1 = fmaf(xt1, wihn, bin);

        // 4 pipelined ds_read_b128: both elements' A fragments
        const f16x8* h0v = reinterpret_cast<const f16x8*>(src[0]);
        const f16x8* h1v = reinterpret_cast<const f16x8*>(src[1]);
        const f16x8 A00 = h0v[grp], A01 = h0v[grp + 4];
        const f16x8 A10 = h1v[grp], A11 = h1v[grp + 4];

        // 12 MFMAs; dependent pairs 6 issue-slots apart (~96cy > dep latency)
        f32x4 p0r = __builtin_amdgcn_mfma_f32_16x16x32_f16(A00, Bf[0][0], zf, 0, 0, 0);
        f32x4 p0z = __builtin_amdgcn_mfma_f32_16x16x32_f16(A00, Bf[1][0], zf, 0, 0, 0);
        f32x4 p0n = __builtin_amdgcn_mfma_f32_16x16x32_f16(A00, Bf[2][0], zf, 0, 0, 0);
        f32x4 p1r = __builtin_amdgcn_mfma_f32_16x16x32_f16(A10, Bf[0][0], zf, 0, 0, 0);
        f32x4 p1z = __builtin_amdgcn_mfma_f32_16x16x32_f16(A10, Bf[1][0], zf, 0, 0, 0);
        f32x4 p1n = __builtin_amdgcn_mfma_f32_16x16x32_f16(A10, Bf[2][0], zf, 0, 0, 0);
        f32x4 q0r = __builtin_amdgcn_mfma_f32_16x16x32_f16(A01, Bf[0][1], p0r, 0, 0, 0);
        f32x4 q0z = __builtin_amdgcn_mfma_f32_16x16x32_f16(A01, Bf[1][1], p0z, 0, 0, 0);
        f32x4 q0n = __builtin_amdgcn_mfma_f32_16x16x32_f16(A01, Bf[2][1], p0n, 0, 0, 0);
        f32x4 q1r = __builtin_amdgcn_mfma_f32_16x16x32_f16(A11, Bf[0][1], p1r, 0, 0, 0);
        f32x4 q1z = __builtin_amdgcn_mfma_f32_16x16x32_f16(A11, Bf[1][1], p1z, 0, 0, 0);
        f32x4 q1n = __builtin_amdgcn_mfma_f32_16x16x32_f16(A11, Bf[2][1], p1n, 0, 0, 0);

        // interleaved gate chains (independent -> trans latency overlaps)
        const float r0 = sigmoid_f(gxr0 + q0r[0]);
        const float r1 = sigmoid_f(gxr1 + q1r[0]);
        const float z0 = sigmoid_f(gxz0 + q0z[0]);
        const float z1 = sigmoid_f(gxz1 + q1z[0]);
        const float n0 = tanh_f(fmaf(r0, q0n[0] + bhn, gxn0));
        const float n1 = tanh_f(fmaf(r1, q1n[0] + bhn, gxn1));
        h0 = fmaf(z0, h0 - n0, n0);
        h1 = fmaf(z1, h1 - n1, n1);

        if (grp == 0) {            // 16 lanes/wave, disjoint units
            dst[0][u] = (f16)h0;
            dst[1][u] = (f16)h1;
        }
        if (j == 63) {
            xw0 = xn0; xw1 = xn1;  // issued 64 steps ago -> long in flight
            const int idx = t + 65 + l;
            xn0 = (idx < T_LEN) ? x[xb0 + idx] : 0.0f;
            xn1 = (idx < T_LEN) ? x[xb1 + idx] : 0.0f;
        }
        // LDS-only drain + barrier: does NOT drain vmcnt -> x prefetch slack
        // survives. DS reads after this can't hoist past the memory clobber.
        asm volatile("s_waitcnt lgkmcnt(0)\n\ts_barrier" ::: "memory");
    };

    for (int t = 0; t < T_LEN; t += 2) {   // T_LEN even: clean pingpong
        step(hbuf[0], hbuf[1], t);
        step(hbuf[1], hbuf[0], t + 1);
    }

    // ---- epilogue: out[b] = h . W_fc + b_fc (fp32, exact register h) ----
    if (grp == 0) { hf32[0][u] = h0; hf32[1][u] = h1; }
    __syncthreads();
    if (tid < 2 * HID) {                   // waves 0,1: one element each
        const int e = tid >> 6;            // 0 or 1
        const int i = tid & 63;
        float v = hf32[e][i] * W_fc[i];
#pragma unroll
        for (int off = 32; off > 0; off >>= 1) v += __shfl_down(v, off);
        if (i == 0) out[b0 + e] = v + b_fc[0];
    }
}

extern "C" void kernel_launch(void* const* d_in, const int* in_sizes, int n_in,
                              void* d_out, int out_size, void* d_ws, size_t ws_size,
                              hipStream_t stream) {
    const float* x    = (const float*)d_in[0];
    const float* W_ih = (const float*)d_in[1];
    const float* W_hh = (const float*)d_in[2];
    const float* b_ih = (const float*)d_in[3];
    const float* b_hh = (const float*)d_in[4];
    const float* W_fc = (const float*)d_in[5];
    const float* b_fc = (const float*)d_in[6];
    float* out = (float*)d_out;

    const int B = 256;  // in_sizes[0] = B*T = 768000 -> B=256, T=3000
    gru_2batch<<<B / 2, 256, 0, stream>>>(x, W_ih, W_hh, b_ih, b_hh, W_fc, b_fc, out);
}

// Round 7
// 690.433 us; speedup vs baseline: 1.3701x; 1.3701x over previous
//
#include <hip/hip_runtime.h>
#include <math.h>

#define T_LEN 3000
#define HID 64

typedef _Float16 f16;
typedef f16 f16x8 __attribute__((ext_vector_type(8)));
typedef float f32x4 __attribute__((ext_vector_type(4)));

#define NLOG2E  (-1.4426950408889634f)   // -log2(e)
#define N2LOG2E (-2.8853900817779268f)   // -2*log2(e)

__device__ __forceinline__ float bcast_lane(float v, int j) {
    return __builtin_bit_cast(float,
        __builtin_amdgcn_readlane(__builtin_bit_cast(int, v), j));
}

// R13: back to R11's 1-element/4-wave shape (R12 lesson: with B=256=#CUs and
// a latency-bound recurrence, wall = stepcy*T -- multi-element blocks can
// never win; only a SHORTER STEP can). R12's busy-CU counters confirmed the
// 16cy/MFMA wave-block model a 4th time (26.2%*738 = 193 = 12*16).
// Cuts to R11's 497cy step, all on the dependent chain:
//  1. C-operand seeding: cr[0]=fma(xt,wihr,br) flows through the p->q MFMA
//     accumulator so q_r[0] IS the sigmoid argument (no post-MFMA adds);
//     n-gate C seeded with constant {bhn,0,0,0} so q_n[0] = an+bhn. Seeds
//     are computed during the ds_read latency (only need xt) -> free.
//  2. Minimal trans tails: r = rcp(1+exp2(s*-log2e)); n = fma(2,
//     rcp(1+exp2(y*-2log2e)), -1). Same math as __expf expansion (~1ulp).
//  3. MFMA issue order r->n->z: q_r lands first, its exp chain overlaps
//     q_n/q_z issue; z's chain parallel to n's, needed only at final fma.
// Barrier: lgkm-only asm (no vmcnt drain -> x-prefetch slack survives; the
// R12 regression is fully explained by 2-batch, not this barrier).
// Fragment math identical to R11 (harness-verified, absmax 4.9e-4).
__global__ __launch_bounds__(256, 1)
void gru_seed(
    const float* __restrict__ x,     // (B, T, 1)
    const float* __restrict__ W_ih,  // (192, 1)
    const float* __restrict__ W_hh,  // (192, 64)
    const float* __restrict__ b_ih,  // (192,)
    const float* __restrict__ b_hh,  // (192,)
    const float* __restrict__ W_fc,  // (1, 64)
    const float* __restrict__ b_fc,  // (1,)
    float* __restrict__ out)         // (B,)
{
    const int tid = threadIdx.x;
    const int w   = tid >> 6;      // wave 0..3 -> owns units 16w..16w+15
    const int l   = tid & 63;
    const int col = l & 15;
    const int grp = l >> 4;        // k-group (redundant dim for gate math)
    const int u   = 16 * w + col;  // this lane's hidden unit
    const int b   = blockIdx.x;
    const long xbase = (long)b * T_LEN;

    __shared__ __align__(16) f16 hbuf[2][HID];  // double-buffered h (f16)
    __shared__ float hf32[HID];                 // epilogue (f32 exact)

    // ---- one-time: this wave's W_hh tiles -> B fragments (f16) ----
    // B slot (lane, elem j) = W_hh[64*g + 16*w + col][8*grp + 32*hf + j]
    f16x8 Bf[3][2];
#pragma unroll
    for (int g = 0; g < 3; ++g) {
#pragma unroll
        for (int hf = 0; hf < 2; ++hf) {
            const float* p = W_hh + (size_t)(64 * g + 16 * w + col) * HID
                           + 8 * grp + 32 * hf;
            const float4 a = *reinterpret_cast<const float4*>(p);
            const float4 c = *reinterpret_cast<const float4*>(p + 4);
            f16x8 v;
            v[0] = (f16)a.x; v[1] = (f16)a.y; v[2] = (f16)a.z; v[3] = (f16)a.w;
            v[4] = (f16)c.x; v[5] = (f16)c.y; v[6] = (f16)c.z; v[7] = (f16)c.w;
            Bf[g][hf] = v;
        }
    }

    // per-unit scalars (lane-redundant across grp, consistent)
    const float wihr = W_ih[u],        wihz = W_ih[64 + u],   wihn = W_ih[128 + u];
    const float br   = b_ih[u]        + b_hh[u];
    const float bz   = b_ih[64 + u]   + b_hh[64 + u];
    const float bin  = b_ih[128 + u];
    const float bhn  = b_hh[128 + u];

    // x window in registers: lane j holds x[t0 + j]; broadcast via readlane
    float xwin = x[xbase + l];
    float xnxt = (64 + l < T_LEN) ? x[xbase + 64 + l] : 0.0f;

    if (tid < HID) hbuf[0][tid] = (f16)0.0f;
    __syncthreads();

    float h = 0.0f;  // this lane's unit value (fp32)
    const f32x4 zf = {0.f, 0.f, 0.f, 0.f};
    // persistent C-seed quads: elems 1..3 stay 0; elem 0 rewritten per step.
    f32x4 cr = zf, cz = zf;
    f32x4 cn = zf; cn[0] = bhn;  // constant seed: q_n[0] = an + bhn

    auto step = [&](const f16* hsrc_raw, f16* hdst, int t) {
        const int j = t & 63;

        // A-fragment loads first (latency-critical)
        const f16x8* hsrc = reinterpret_cast<const f16x8*>(hsrc_raw);
        const f16x8 A0 = hsrc[grp];       // h[8g..8g+7]       (ds_read_b128)
        const f16x8 A1 = hsrc[grp + 4];   // h[32+8g..32+8g+7]

        // seeds: only need xt -> computed during the ds_read latency
        const float xt  = bcast_lane(xwin, j);
        cr[0] = fmaf(xt, wihr, br);
        cz[0] = fmaf(xt, wihz, bz);
        const float gxn = fmaf(xt, wihn, bin);

        // 6 MFMAs, r first so its result lands earliest
        f32x4 pr = __builtin_amdgcn_mfma_f32_16x16x32_f16(A0, Bf[0][0], cr, 0, 0, 0);
        f32x4 pn = __builtin_amdgcn_mfma_f32_16x16x32_f16(A0, Bf[2][0], cn, 0, 0, 0);
        f32x4 pz = __builtin_amdgcn_mfma_f32_16x16x32_f16(A0, Bf[1][0], cz, 0, 0, 0);
        f32x4 qr = __builtin_amdgcn_mfma_f32_16x16x32_f16(A1, Bf[0][1], pr, 0, 0, 0);
        f32x4 qn = __builtin_amdgcn_mfma_f32_16x16x32_f16(A1, Bf[2][1], pn, 0, 0, 0);
        f32x4 qz = __builtin_amdgcn_mfma_f32_16x16x32_f16(A1, Bf[1][1], pz, 0, 0, 0);

        // minimal dependent tails (exp2-form == __expf expansion, ~1ulp)
        const float r = __builtin_amdgcn_rcpf(
            1.0f + __builtin_amdgcn_exp2f(qr[0] * NLOG2E));
        const float y = fmaf(r, qn[0], gxn);           // qn[0] = an + bhn
        const float z = __builtin_amdgcn_rcpf(
            1.0f + __builtin_amdgcn_exp2f(qz[0] * NLOG2E));
        const float n = fmaf(2.0f, __builtin_amdgcn_rcpf(
            1.0f + __builtin_amdgcn_exp2f(y * N2LOG2E)), -1.0f);
        h = fmaf(z, h - n, n);  // (1-z)*n + z*h

        if (grp == 0) hdst[u] = (f16)h;   // 16 lanes/wave, disjoint units
        if (j == 63) {
            xwin = xnxt;                   // issued 64 steps ago -> landed
            const int idx = t + 65 + l;
            xnxt = (idx < T_LEN) ? x[xbase + idx] : 0.0f;
        }
        // LDS-only drain + barrier (no vmcnt drain -> x slack survives)
        asm volatile("s_waitcnt lgkmcnt(0)\n\ts_barrier" ::: "memory");
    };

    for (int t = 0; t < T_LEN; t += 2) {   // T_LEN even: clean pingpong
        step(hbuf[0], hbuf[1], t);
        step(hbuf[1], hbuf[0], t + 1);
    }

    // ---- epilogue: out[b] = h . W_fc + b_fc (fp32, exact register h) ----
    if (grp == 0) hf32[u] = h;
    __syncthreads();
    if (tid < HID) {
        float v = hf32[tid] * W_fc[tid];
#pragma unroll
        for (int off = 32; off > 0; off >>= 1) v += __shfl_down(v, off);
        if (tid == 0) out[b] = v + b_fc[0];
    }
}

extern "C" void kernel_launch(void* const* d_in, const int* in_sizes, int n_in,
                              void* d_out, int out_size, void* d_ws, size_t ws_size,
                              hipStream_t stream) {
    const float* x    = (const float*)d_in[0];
    const float* W_ih = (const float*)d_in[1];
    const float* W_hh = (const float*)d_in[2];
    const float* b_ih = (const float*)d_in[3];
    const float* b_hh = (const float*)d_in[4];
    const float* W_fc = (const float*)d_in[5];
    const float* b_fc = (const float*)d_in[6];
    float* out = (float*)d_out;

    const int B = 256;  // in_sizes[0] = B*T = 768000 -> B=256, T=3000
    gru_seed<<<B, 256, 0, stream>>>(x, W_ih, W_hh, b_ih, b_hh, W_fc, b_fc, out);
}

// Round 8
// 636.816 us; speedup vs baseline: 1.4854x; 1.0842x over previous
//
#include <hip/hip_runtime.h>
#include <math.h>

#define T_LEN 3000
#define HID 64

typedef _Float16 f16;
typedef f16 f16x8 __attribute__((ext_vector_type(8)));
typedef float f32x4 __attribute__((ext_vector_type(4)));

#define NLOG2E  (-1.4426950408889634f)   // -log2(e)
#define N2LOG2E (-2.8853900817779268f)   // -2*log2(e)

__device__ __forceinline__ float bcast_lane(float v, int j) {
    return __builtin_bit_cast(float,
        __builtin_amdgcn_readlane(__builtin_bit_cast(int, v), j));
}

// R14: R11 structure (4 waves, 6 MFMA/wave, post-MFMA adds -- R13's C-seeding
// regressed +27cy: per-step C-quad rebuild/copy). Tail compression with zero
// added on-path ops:
//  1. exp2-arg fusion: arg = (gx+q0)*c = fmaf(q0, c, pre) with pre =
//     fmaf(xt, wih*c, b*c) computed OFF-path (scaled consts hoisted).
//     r/z chains: extract -> fma -> exp2 -> add -> rcp.  n-gate: hn2 =
//     fmaf(qn0, N2LOG2E, bhn2) runs parallel to r-chain; after r one
//     fma -> exp2 -> add -> rcp -> fma(2,..,-1).
//  2. h = fmaf(1-z, n, z*h): omz/zh precomputed during n-chain -> single
//     fma after n (was sub+fma).
//  3. unconditional ds_write (4-way same-address, same value, ~2cy) instead
//     of if(grp==0) exec-mask dance (~10cy SALU on path). LDS addresses
//     hoisted to loop-invariant pointers.
// Barrier: lgkm-only asm (no vmcnt drain -> x-prefetch slack survives).
// Budget model (4x confirmed 16cy/MFMA wave-block): 497cy = 40 barrier +
// 125 ds_read + 128 MFMA + ~100 tail + ~10 write + ~95 fat; this attacks
// the tail+fat. Floor ~400cy (=500us). Falsification: >=620us => codegen
// floor reached.
__global__ __launch_bounds__(256, 1)
void gru_tail(
    const float* __restrict__ x,     // (B, T, 1)
    const float* __restrict__ W_ih,  // (192, 1)
    const float* __restrict__ W_hh,  // (192, 64)
    const float* __restrict__ b_ih,  // (192,)
    const float* __restrict__ b_hh,  // (192,)
    const float* __restrict__ W_fc,  // (1, 64)
    const float* __restrict__ b_fc,  // (1,)
    float* __restrict__ out)         // (B,)
{
    const int tid = threadIdx.x;
    const int w   = tid >> 6;      // wave 0..3 -> owns units 16w..16w+15
    const int l   = tid & 63;
    const int col = l & 15;
    const int grp = l >> 4;        // k-group (redundant dim for gate math)
    const int u   = 16 * w + col;  // this lane's hidden unit
    const int b   = blockIdx.x;
    const long xbase = (long)b * T_LEN;

    __shared__ __align__(16) f16 hbuf[2][HID];  // double-buffered h (f16)
    __shared__ float hf32[HID];                 // epilogue (f32 exact)

    // ---- one-time: this wave's W_hh tiles -> B fragments (f16) ----
    // B slot (lane, elem j) = W_hh[64*g + 16*w + col][8*grp + 32*hf + j]
    f16x8 Bf[3][2];
#pragma unroll
    for (int g = 0; g < 3; ++g) {
#pragma unroll
        for (int hf = 0; hf < 2; ++hf) {
            const float* p = W_hh + (size_t)(64 * g + 16 * w + col) * HID
                           + 8 * grp + 32 * hf;
            const float4 a = *reinterpret_cast<const float4*>(p);
            const float4 c = *reinterpret_cast<const float4*>(p + 4);
            f16x8 v;
            v[0] = (f16)a.x; v[1] = (f16)a.y; v[2] = (f16)a.z; v[3] = (f16)a.w;
            v[4] = (f16)c.x; v[5] = (f16)c.y; v[6] = (f16)c.z; v[7] = (f16)c.w;
            Bf[g][hf] = v;
        }
    }

    // per-unit scalars, pre-scaled by the exp2 constants (off-path fusion)
    const float wihr2 = W_ih[u]        * NLOG2E;
    const float wihz2 = W_ih[64 + u]   * NLOG2E;
    const float wihn2 = W_ih[128 + u]  * N2LOG2E;
    const float br2   = (b_ih[u]        + b_hh[u])        * NLOG2E;
    const float bz2   = (b_ih[64 + u]   + b_hh[64 + u])   * NLOG2E;
    const float bin2  = b_ih[128 + u]  * N2LOG2E;
    const float bhn2  = b_hh[128 + u]  * N2LOG2E;

    // x window in registers: lane j holds x[t0 + j]; broadcast via readlane
    float xwin = x[xbase + l];
    float xnxt = (64 + l < T_LEN) ? x[xbase + 64 + l] : 0.0f;

    if (tid < HID) hbuf[0][tid] = (f16)0.0f;
    __syncthreads();

    float h = 0.0f;  // this lane's unit value (fp32)
    const f32x4 zf = {0.f, 0.f, 0.f, 0.f};

    // loop-invariant LDS addresses
    const f16x8* s0A = reinterpret_cast<const f16x8*>(hbuf[0]) + grp;
    const f16x8* s0B = s0A + 4;
    const f16x8* s1A = reinterpret_cast<const f16x8*>(hbuf[1]) + grp;
    const f16x8* s1B = s1A + 4;
    f16* d0 = &hbuf[0][u];
    f16* d1 = &hbuf[1][u];

    auto step = [&](const f16x8* aP, const f16x8* bP, f16* dstu, int t) {
        const int j = t & 63;

        const f16x8 A0 = *aP;             // h[8g..8g+7]       (ds_read_b128)
        const f16x8 A1 = *bP;             // h[32+8g..32+8g+7]

        // off-path pre-terms (only need xt; compute during ds_read latency)
        const float xt    = bcast_lane(xwin, j);
        const float pre_r = fmaf(xt, wihr2, br2);
        const float pre_z = fmaf(xt, wihz2, bz2);
        const float pre_n = fmaf(xt, wihn2, bin2);

        // 6 MFMAs (16cy wave-block each); dep pairs 3 slots apart
        f32x4 pr = __builtin_amdgcn_mfma_f32_16x16x32_f16(A0, Bf[0][0], zf, 0, 0, 0);
        f32x4 pz = __builtin_amdgcn_mfma_f32_16x16x32_f16(A0, Bf[1][0], zf, 0, 0, 0);
        f32x4 pn = __builtin_amdgcn_mfma_f32_16x16x32_f16(A0, Bf[2][0], zf, 0, 0, 0);
        f32x4 qr = __builtin_amdgcn_mfma_f32_16x16x32_f16(A1, Bf[0][1], pr, 0, 0, 0);
        f32x4 qz = __builtin_amdgcn_mfma_f32_16x16x32_f16(A1, Bf[1][1], pz, 0, 0, 0);
        f32x4 qn = __builtin_amdgcn_mfma_f32_16x16x32_f16(A1, Bf[2][1], pn, 0, 0, 0);

        // r-chain: fma -> exp2 -> add -> rcp   (~32cy post-extract)
        const float r = __builtin_amdgcn_rcpf(
            1.0f + __builtin_amdgcn_exp2f(fmaf(qr[0], NLOG2E, pre_r)));
        // parallel with r-chain:
        const float hn2 = fmaf(qn[0], N2LOG2E, bhn2);
        const float z = __builtin_amdgcn_rcpf(
            1.0f + __builtin_amdgcn_exp2f(fmaf(qz[0], NLOG2E, pre_z)));
        const float zh  = z * h;
        const float omz = 1.0f - z;
        // n-chain after r: fma -> exp2 -> add -> rcp -> fma
        const float n = fmaf(2.0f, __builtin_amdgcn_rcpf(
            1.0f + __builtin_amdgcn_exp2f(fmaf(r, hn2, pre_n))), -1.0f);
        h = fmaf(omz, n, zh);   // (1-z)*n + z*h

        *dstu = (f16)h;         // unconditional: 4 lanes, same addr+value
        if (j == 63) {
            xwin = xnxt;                   // issued 64 steps ago -> landed
            const int idx = t + 65 + l;
            xnxt = (idx < T_LEN) ? x[xbase + idx] : 0.0f;
        }
        // LDS-only drain + barrier (no vmcnt drain -> x slack survives)
        asm volatile("s_waitcnt lgkmcnt(0)\n\ts_barrier" ::: "memory");
    };

    for (int t = 0; t < T_LEN; t += 2) {   // T_LEN even: clean pingpong
        step(s0A, s0B, d1, t);
        step(s1A, s1B, d0, t + 1);
    }

    // ---- epilogue: out[b] = h . W_fc + b_fc (fp32, exact register h) ----
    hf32[u] = h;   // unconditional, same value per u
    __syncthreads();
    if (tid < HID) {
        float v = hf32[tid] * W_fc[tid];
#pragma unroll
        for (int off = 32; off > 0; off >>= 1) v += __shfl_down(v, off);
        if (tid == 0) out[b] = v + b_fc[0];
    }
}

extern "C" void kernel_launch(void* const* d_in, const int* in_sizes, int n_in,
                              void* d_out, int out_size, void* d_ws, size_t ws_size,
                              hipStream_t stream) {
    const float* x    = (const float*)d_in[0];
    const float* W_ih = (const float*)d_in[1];
    const float* W_hh = (const float*)d_in[2];
    const float* b_ih = (const float*)d_in[3];
    const float* b_hh = (const float*)d_in[4];
    const float* W_fc = (const float*)d_in[5];
    const float* b_fc = (const float*)d_in[6];
    float* out = (float*)d_out;

    const int B = 256;  // in_sizes[0] = B*T = 768000 -> B=256, T=3000
    gru_tail<<<B, 256, 0, stream>>>(x, W_ih, W_hh, b_ih, b_hh, W_fc, b_fc, out);
}